// Round 1
// baseline (42.373 us; speedup 1.0000x reference)
//
#include <hip/hip_runtime.h>

#define H_DIM 1024
#define H4 (H_DIM / 4)   // float4 elements per row = 256

// Pass 1: derive each word's [start, count) from segment_ids.
// Segments are contiguous token spans, so start = min token index, and
// count = number of tokens with that id. Generic: handles empty segments.
__global__ void WordPooling_spans_kernel(const int* __restrict__ seg,
                                         int n_tokens,
                                         int* __restrict__ starts,
                                         int* __restrict__ counts) {
    int t = blockIdx.x * blockDim.x + threadIdx.x;
    if (t < n_tokens) {
        int s = seg[t];
        atomicAdd(&counts[s], 1);
        atomicMin(&starts[s], t);
    }
}

// Pass 2: one block per word; 256 threads each own one float4 (16B) of the
// H=1024 row. Reads are fully coalesced: the block sweeps each 4KiB token
// row contiguously. Mean = sum / max(count,1); empty word -> 0.
__global__ void WordPooling_pool_kernel(const float* __restrict__ x,
                                        const int* __restrict__ starts,
                                        const int* __restrict__ counts,
                                        float* __restrict__ out) {
    int w = blockIdx.x;
    int h = threadIdx.x;            // float4 index within the row
    int cnt = counts[w];
    int st  = starts[w];

    const float4* x4 = (const float4*)x;
    float4 acc = make_float4(0.f, 0.f, 0.f, 0.f);
    for (int i = 0; i < cnt; ++i) {
        float4 v = x4[(size_t)(st + i) * H4 + h];
        acc.x += v.x; acc.y += v.y; acc.z += v.z; acc.w += v.w;
    }
    float inv = 1.0f / fmaxf((float)cnt, 1.0f);
    float4 r = make_float4(acc.x * inv, acc.y * inv, acc.z * inv, acc.w * inv);
    ((float4*)out)[(size_t)w * H4 + h] = r;
}

extern "C" void kernel_launch(void* const* d_in, const int* in_sizes, int n_in,
                              void* d_out, int out_size, void* d_ws, size_t ws_size,
                              hipStream_t stream) {
    const float* x  = (const float*)d_in[0];
    const int* seg  = (const int*)d_in[1];
    int n_tokens    = in_sizes[1];          // B*S = 32768
    int W           = out_size / H_DIM;     // num_segments = 8192

    int* starts = (int*)d_ws;
    int* counts = starts + W;

    // Reset scratch every call (harness does not re-poison between replays).
    // 0x7F7F7F7F ~ 2.1e9 acts as +inf for atomicMin over token indices.
    hipMemsetAsync(starts, 0x7F, (size_t)W * sizeof(int), stream);
    hipMemsetAsync(counts, 0x00, (size_t)W * sizeof(int), stream);

    WordPooling_spans_kernel<<<(n_tokens + 255) / 256, 256, 0, stream>>>(
        seg, n_tokens, starts, counts);

    WordPooling_pool_kernel<<<W, H4, 0, stream>>>(
        x, starts, counts, (float*)d_out);
}

// Round 2
// 34.705 us; speedup vs baseline: 1.2210x; 1.2210x over previous
//
#include <hip/hip_runtime.h>

#define H_DIM 1024
#define H4 (H_DIM / 4)   // float4 elements per row = 256

// One block per word, 256 threads each owning one float4 (16B) of the H=1024
// row. segment_ids is non-decreasing (contiguous token spans), so the word's
// token range [st, en) is found by binary search — uniform broadcast loads,
// all cache-hit after the first few blocks. Single dispatch: no scratch, no
// atomics, no memsets.
__global__ void WordPooling_fused_kernel(const float* __restrict__ x,
                                         const int* __restrict__ seg,
                                         int n_tokens,
                                         float* __restrict__ out) {
    int w = blockIdx.x;
    int h = threadIdx.x;            // float4 index within the row

    // lower_bound: first t with seg[t] >= w
    int lo = 0, hi = n_tokens;
    while (lo < hi) {
        int mid = (lo + hi) >> 1;
        if (seg[mid] < w) lo = mid + 1; else hi = mid;
    }
    int st = lo;
    // upper_bound: first t with seg[t] > w
    hi = n_tokens;
    while (lo < hi) {
        int mid = (lo + hi) >> 1;
        if (seg[mid] <= w) lo = mid + 1; else hi = mid;
    }
    int cnt = lo - st;

    const float4* x4 = (const float4*)x;
    float4 acc = make_float4(0.f, 0.f, 0.f, 0.f);
    for (int i = 0; i < cnt; ++i) {
        float4 v = x4[(size_t)(st + i) * H4 + h];
        acc.x += v.x; acc.y += v.y; acc.z += v.z; acc.w += v.w;
    }
    float inv = 1.0f / fmaxf((float)cnt, 1.0f);
    float4 r = make_float4(acc.x * inv, acc.y * inv, acc.z * inv, acc.w * inv);
    ((float4*)out)[(size_t)w * H4 + h] = r;
}

extern "C" void kernel_launch(void* const* d_in, const int* in_sizes, int n_in,
                              void* d_out, int out_size, void* d_ws, size_t ws_size,
                              hipStream_t stream) {
    const float* x  = (const float*)d_in[0];
    const int* seg  = (const int*)d_in[1];
    int n_tokens    = in_sizes[1];          // B*S = 32768
    int W           = out_size / H_DIM;     // num_segments = 8192

    WordPooling_fused_kernel<<<W, H4, 0, stream>>>(x, seg, n_tokens, (float*)d_out);
}

// Round 3
// 31.403 us; speedup vs baseline: 1.3493x; 1.1051x over previous
//
#include <hip/hip_runtime.h>

#define H_DIM 1024
#define H4 (H_DIM / 4)   // float4 elements per row = 256

typedef float f32x4 __attribute__((ext_vector_type(4)));

// One block per word, 256 threads each owning one float4 (16B) of the H=1024
// row. segment_ids is non-decreasing (contiguous token spans): start via one
// binary search (uniform cached loads), count via short forward scan.
// x (128 MiB) is read-once and out (32 MiB) write-once -> non-temporal
// loads/stores to keep the dead lines out of L2 and run at pure stream rate.
__global__ void WordPooling_fused_kernel(const float* __restrict__ x,
                                         const int* __restrict__ seg,
                                         int n_tokens,
                                         float* __restrict__ out) {
    int w = blockIdx.x;
    int h = threadIdx.x;            // float4 index within the row

    // lower_bound: first t with seg[t] >= w
    int lo = 0, hi = n_tokens;
    while (lo < hi) {
        int mid = (lo + hi) >> 1;
        if (seg[mid] < w) lo = mid + 1; else hi = mid;
    }
    int st = lo;
    // forward scan for span length (avg ~4, all L1-hit)
    int cnt = 0;
    while (st + cnt < n_tokens && seg[st + cnt] == w) ++cnt;

    const f32x4* p = (const f32x4*)x + (size_t)st * H4 + h;
    f32x4 acc = (f32x4)(0.0f);
    if (cnt == 4) {
        // fast path: 4 independent loads in flight, sequential-order sum
        f32x4 v0 = __builtin_nontemporal_load(p);
        f32x4 v1 = __builtin_nontemporal_load(p + H4);
        f32x4 v2 = __builtin_nontemporal_load(p + 2 * H4);
        f32x4 v3 = __builtin_nontemporal_load(p + 3 * H4);
        acc = ((v0 + v1) + v2) + v3;
        acc *= 0.25f;
    } else {
        for (int i = 0; i < cnt; ++i)
            acc += __builtin_nontemporal_load(p + (size_t)i * H4);
        acc *= 1.0f / fmaxf((float)cnt, 1.0f);
    }
    __builtin_nontemporal_store(acc, (f32x4*)out + (size_t)w * H4 + h);
}

extern "C" void kernel_launch(void* const* d_in, const int* in_sizes, int n_in,
                              void* d_out, int out_size, void* d_ws, size_t ws_size,
                              hipStream_t stream) {
    const float* x  = (const float*)d_in[0];
    const int* seg  = (const int*)d_in[1];
    int n_tokens    = in_sizes[1];          // B*S = 32768
    int W           = out_size / H_DIM;     // num_segments = 8192

    WordPooling_fused_kernel<<<W, H4, 0, stream>>>(x, seg, n_tokens, (float*)d_out);
}